// Round 1
// baseline (534.723 us; speedup 1.0000x reference)
//
#include <hip/hip_runtime.h>

// Problem constants (from reference)
constexpr int BS_TOTAL = 16 * 32;   // B*S = 512 sentences
constexpr int L = 256;              // seq len
constexpr int D = 768;              // hidden
constexpr int P = 16;               // predicates per sentence
constexpr int T = 4;                // tokens per span
constexpr int PAD = 1;
constexpr int NROWS = 3 * P;        // 48 span rows (pred, arg0, arg1)

constexpr int GROUPS = 4;           // row-parallel groups
constexpr int LANES  = D / 4;       // 192 lanes, one float4 of D each
constexpr int NTHREADS = GROUPS * LANES; // 768 threads = 12 waves

__global__ __launch_bounds__(NTHREADS, 1) void srl_kernel(
    const int*   __restrict__ sent_ids,   // [BS, L]
    const int*   __restrict__ attn_mask,  // [BS, L]
    const int*   __restrict__ pred_ids,   // [BS, P, T]
    const int*   __restrict__ arg0_ids,   // [BS, P, T]
    const int*   __restrict__ arg1_ids,   // [BS, P, T]
    const float* __restrict__ emb,        // [BS, L, D]
    float*       __restrict__ out)        // concat: sent[BS,D] | pred[BS,P,D] | arg0 | arg1
{
    const int bs = blockIdx.x;
    const int t  = threadIdx.x;
    const int g  = t / LANES;   // row group 0..3
    const int c  = t % LANES;   // column quad: cols 4c..4c+3

    __shared__ int            s_span[NROWS * T];       // 192 ints, s_span[r*4+k]
    __shared__ int            s_act[L];                // compacted active-l list
    __shared__ unsigned short s_list[NROWS][L];        // (cnt<<8)|l per row
    __shared__ int            s_rown[NROWS];
    __shared__ int            s_nact;
    __shared__ float          s_part[(GROUPS - 1) * D]; // sentence partials of groups 1..3

    // --- init counters ---
    if (t < NROWS) s_rown[t] = 0;
    if (t == NTHREADS - 1) s_nact = 0;

    // --- load span ids: row r = type*16+p, flat layout matches input layout ---
    if (t < 64)       s_span[t] = pred_ids[bs * 64 + t];
    else if (t < 128) s_span[t] = arg0_ids[bs * 64 + (t - 64)];
    else if (t < 192) s_span[t] = arg1_ids[bs * 64 + (t - 128)];

    // --- attn-gated token key for l = t ---
    int key = -1;
    if (t < L) {
        const int sid = sent_ids[bs * L + t];
        const int am  = attn_mask[bs * L + t];
        key = (am != 0) ? sid : -1;   // token ids are >= 0, so -1 never matches
    }
    __syncthreads();

    // --- phase 1: sparse match lists (threads 0..255, one l each) ---
    if (t < L) {
        if (key >= 0) {
            const int pos = atomicAdd(&s_nact, 1);
            s_act[pos] = t;
        }
        for (int r = 0; r < NROWS; ++r) {
            int cnt = 0;
            #pragma unroll
            for (int k = 0; k < T; ++k) {
                const int id = s_span[r * T + k];      // wave-uniform -> LDS broadcast
                cnt += (id != PAD && id == key) ? 1 : 0;
            }
            if (cnt > 0) {
                const int pos = atomicAdd(&s_rown[r], 1);
                s_list[r][pos] = (unsigned short)((cnt << 8) | t);
            }
        }
    }
    __syncthreads();

    const size_t ebase = (size_t)bs * (L * D);
    const int nact = s_nact;

    // --- phase 2: sentence average (stream active rows once, float4 coalesced) ---
    float4 acc = make_float4(0.f, 0.f, 0.f, 0.f);
    #pragma unroll 4
    for (int i = g; i < nact; i += GROUPS) {
        const int l = s_act[i];
        const float4 v = *(const float4*)(emb + ebase + (size_t)l * D + 4 * c);
        acc.x += v.x; acc.y += v.y; acc.z += v.z; acc.w += v.w;
    }
    if (g > 0) *(float4*)&s_part[(g - 1) * D + 4 * c] = acc;
    __syncthreads();
    if (g == 0) {
        #pragma unroll
        for (int q = 0; q < GROUPS - 1; ++q) {
            const float4 o = *(const float4*)&s_part[q * D + 4 * c];
            acc.x += o.x; acc.y += o.y; acc.z += o.z; acc.w += o.w;
        }
        const float inv = 1.0f / (float)(nact > 0 ? nact : 1);
        float4 rr = make_float4(acc.x * inv, acc.y * inv, acc.z * inv, acc.w * inv);
        *(float4*)(out + (size_t)bs * D + 4 * c) = rr;
    }

    // --- phase 3: span rows — gather the few matched embedding rows (cache-hot) ---
    float* argbase = out + (size_t)BS_TOTAL * D;               // after sentence block
    const size_t argstride = (size_t)BS_TOTAL * P * D;         // per-type block
    for (int r = g; r < NROWS; r += GROUPS) {
        const int n   = s_rown[r];
        const int typ = r >> 4;
        const int p   = r & (P - 1);
        float* op = argbase + (size_t)typ * argstride + ((size_t)bs * P + p) * D + 4 * c;
        float4 a = make_float4(0.f, 0.f, 0.f, 0.f);
        int den = 0;
        for (int i = 0; i < n; ++i) {
            const unsigned int e = s_list[r][i];               // wave-uniform -> broadcast
            const int   l = (int)(e & 255u);
            const int   w = (int)(e >> 8);
            den += w;
            const float wf = (float)w;
            const float4 v = *(const float4*)(emb + ebase + (size_t)l * D + 4 * c);
            a.x += wf * v.x; a.y += wf * v.y; a.z += wf * v.z; a.w += wf * v.w;
        }
        if (n > 0) {
            const float inv = 1.0f / (float)den;               // den >= 1 when n > 0
            a.x *= inv; a.y *= inv; a.z *= inv; a.w *= inv;
        }
        *(float4*)op = a;   // n == 0 -> zeros (reference: where(den>0, ., 0))
    }
}

extern "C" void kernel_launch(void* const* d_in, const int* in_sizes, int n_in,
                              void* d_out, int out_size, void* d_ws, size_t ws_size,
                              hipStream_t stream) {
    srl_kernel<<<dim3(BS_TOTAL), dim3(NTHREADS), 0, stream>>>(
        (const int*)d_in[0],   // sentence_ids
        (const int*)d_in[1],   // sentence_attention_masks
        (const int*)d_in[2],   // predicate_ids
        (const int*)d_in[3],   // arg0_ids
        (const int*)d_in[4],   // arg1_ids
        (const float*)d_in[5], // token_embeddings
        (float*)d_out);
}